// Round 4
// baseline (325.728 us; speedup 1.0000x reference)
//
#include <hip/hip_runtime.h>
#include <math.h>

#define BATCH 128
#define NANCH 8400
#define NMSK  300
#define KPT   17
#define OUTC  56    // 4 box + 1 score + 34 kpt + 17 vis
#define CAND  1024  // candidate slots (>=300 + tie margin; was 768)
#define NTHR  1024
#define NBIN  8192  // 13-bit bins: sign(0)+exp(8)+mant(5) of positive f32
#define BSHIFT 19

__device__ __forceinline__ void prior_of(int i, float& stride, float& cx, float& cy) {
    int row, col;
    if (i < 6400)      { stride = 8.0f;  row = i / 80;              col = i - row * 80; }
    else if (i < 8000) { int ii = i - 6400; stride = 16.0f; row = ii / 40; col = ii - row * 40; }
    else               { int ii = i - 8000; stride = 32.0f; row = ii / 20; col = ii - row * 20; }
    cx = ((float)col + 0.5f) * stride;
    cy = ((float)row + 0.5f) * stride;
}

// ---------------------------------------------------------------------------
// K1: all B*N fused scores (np-f32-exact) -> sc bits in workspace.
// R3 rocprof proved workspace poison-fill is UNCONDITIONAL, so ws use is free.
// DO NOT change this math: bit-exact vs np reference (absmax 0.0).
// Grid: 268800 float4 groups / 256 = 1050 blocks exactly (no bounds check).
// ---------------------------------------------------------------------------
__global__ __launch_bounds__(256) void scores_kernel(
    const float* __restrict__ cls, const float* __restrict__ obj,
    unsigned int* __restrict__ sc)
{
    int i = blockIdx.x * 256 + threadIdx.x;   // float4 group index
    float4 cv = ((const float4*)cls)[i];
    float4 ov = ((const float4*)obj)[i];
    float sa0 = 1.0f / (1.0f + (float)exp(-(double)cv.x));
    float sa1 = 1.0f / (1.0f + (float)exp(-(double)cv.y));
    float sa2 = 1.0f / (1.0f + (float)exp(-(double)cv.z));
    float sa3 = 1.0f / (1.0f + (float)exp(-(double)cv.w));
    float so0 = 1.0f / (1.0f + (float)exp(-(double)ov.x));
    float so1 = 1.0f / (1.0f + (float)exp(-(double)ov.y));
    float so2 = 1.0f / (1.0f + (float)exp(-(double)ov.z));
    float so3 = 1.0f / (1.0f + (float)exp(-(double)ov.w));
    uint4 r;
    r.x = __float_as_uint(sa0 * so0);
    r.y = __float_as_uint(sa1 * so1);
    r.z = __float_as_uint(sa2 * so2);
    r.w = __float_as_uint(sa3 * so3);
    ((uint4*)sc)[i] = r;
}

// ---------------------------------------------------------------------------
// K2: per-batch select + NMS. 128 blocks x 1024.
//   Single-pass 8192-bin histogram select (replaces 4 radix rounds): bin =
//   key>>19 is monotone in key for positive f32, pivot bin p satisfies
//   suf[p] >= 300 > suf[p+1]; candidates = keys >= (p<<19); exact order via
//   rank loop (key desc, idx asc == lax.top_k), M ~= 300-350 at 13-bit bins.
//   Greedy NMS scan: mask rows distributed across wave0 lanes, serial chain
//   through SGPRs via readlane (~10-15cy/step) instead of dependent LDS
//   reads (~120cy/step).
// ---------------------------------------------------------------------------
__global__ __launch_bounds__(NTHR) void select_kernel(
    const unsigned int* __restrict__ sc_g, const float* __restrict__ bbox,
    float* __restrict__ out, int* __restrict__ sidx_g)
{
    const int b = blockIdx.x;
    const int tid = threadIdx.x;
    const int lane = tid & 63;
    const int wv = tid >> 6;

    __shared__ __align__(16) unsigned int sc[NANCH];     // 33600 B
    __shared__ __align__(16) unsigned int hist[NBIN];    // 32768 B (reused as suf)
    __shared__ unsigned int wtot[16], wab[16];
    __shared__ unsigned int sh_pivot, sh_cnt;
    __shared__ unsigned long long ckey[CAND];            // 8192 B
    __shared__ float bx1[NMSK], by1[NMSK], bx2[NMSK], by2[NMSK], area[NMSK];
    __shared__ float sval[NMSK];
    __shared__ int   sidx[NMSK];
    __shared__ unsigned long long supl[NMSK * 6];        // 14400 B
    __shared__ unsigned long long keepw[5];

    // ---- stage score bits (uint4) + zero hist ----
    {
        const uint4* s4 = (const uint4*)(sc_g + (size_t)b * NANCH);
        uint4* d4 = (uint4*)sc;
        for (int i = tid; i < NANCH / 4; i += NTHR) d4[i] = s4[i];
        uint4 z; z.x = z.y = z.z = z.w = 0u;
        uint4* h4 = (uint4*)hist;
        for (int i = tid; i < NBIN / 4; i += NTHR) h4[i] = z;
        if (tid == 0) sh_cnt = 0u;
    }
    __syncthreads();

    // ---- 8192-bin histogram ----
    for (int i = tid; i < NANCH; i += NTHR) atomicAdd(&hist[sc[i] >> BSHIFT], 1u);
    __syncthreads();

    // ---- suffix scan (in-place): thread owns bins [8t, 8t+8) ----
    unsigned int s7[8];
    {
        uint4 a = ((uint4*)hist)[2 * tid];
        uint4 c = ((uint4*)hist)[2 * tid + 1];
        unsigned int h0 = a.x, h1 = a.y, h2 = a.z, h3 = a.w;
        unsigned int h4 = c.x, h5 = c.y, h6 = c.z, h7 = c.w;
        s7[7] = h7;
        s7[6] = s7[7] + h6; s7[5] = s7[6] + h5; s7[4] = s7[5] + h4;
        s7[3] = s7[4] + h3; s7[2] = s7[3] + h2; s7[1] = s7[2] + h1;
        s7[0] = s7[1] + h0;
    }
    unsigned int T = s7[0];
    unsigned int v = T;
    #pragma unroll
    for (int d = 1; d < 64; d <<= 1) {
        unsigned int t2 = (unsigned int)__shfl_down((int)v, d, 64);
        if (lane + d < 64) v += t2;       // v = inclusive suffix over lanes >= lane
    }
    unsigned int aiw = v - T;             // sum over lanes > lane (higher bins)
    if (lane == 0) wtot[wv] = v;          // wave total
    __syncthreads();
    if (tid < 16) {
        unsigned int wa = 0;
        for (int q = tid + 1; q < 16; ++q) wa += wtot[q];
        wab[tid] = wa;                    // sum over waves > w
    }
    __syncthreads();
    {
        unsigned int ag = wab[wv] + aiw;
        #pragma unroll
        for (int k = 0; k < 8; ++k) hist[8 * tid + k] = ag + s7[k];  // hist := suf
    }
    __syncthreads();

    // ---- pivot: the unique bin with suf[p] >= 300 > suf[p+1] ----
    #pragma unroll
    for (int k = 0; k < 8; ++k) {
        unsigned int bin = 8 * (unsigned)tid + k;
        unsigned int ge = hist[bin];
        unsigned int gn = (bin < NBIN - 1) ? hist[bin + 1] : 0u;
        if (ge >= NMSK && gn < NMSK) sh_pivot = bin;
    }
    __syncthreads();
    unsigned int pivot_bits = sh_pivot << BSHIFT;

    // ---- compact all keys >= pivot (wave-aggregated counter) ----
    for (int base = 0; base < NANCH; base += NTHR) {
        int i = base + tid;
        bool valid = (i < NANCH);
        unsigned int key = valid ? sc[i] : 0u;
        bool pred = valid && (key >= pivot_bits);
        unsigned long long m = __ballot(pred);
        unsigned int cnt = (unsigned int)__popcll(m);
        unsigned int wbase = 0u;
        if (lane == 0 && cnt) wbase = atomicAdd(&sh_cnt, cnt);
        wbase = (unsigned int)__shfl((int)wbase, 0, 64);
        if (pred) {
            unsigned int p = wbase + (unsigned int)__popcll(m & ((1ull << lane) - 1ull));
            if (p < CAND)
                ckey[p] = ((unsigned long long)key << 32)
                        | (unsigned long long)(0xFFFFFFFFu - (unsigned int)i);
        }
    }
    __syncthreads();
    unsigned int M = sh_cnt; if (M > CAND) M = CAND;

    // ---- rank order (score desc, idx asc == lax.top_k) ----
    if (tid < (int)M) {
        unsigned long long mine = ckey[tid];
        int rank = 0;
        for (unsigned int t2 = 0; t2 < M; ++t2) rank += (ckey[t2] > mine) ? 1 : 0;
        if (rank < NMSK) {
            sidx[rank] = (int)(0xFFFFFFFFu - (unsigned int)(mine & 0xFFFFFFFFull));
            sval[rank] = __uint_as_float((unsigned int)(mine >> 32));
        }
    }
    __syncthreads();

    // ---- decode the 300 boxes ----
    if (tid < NMSK) {
        int j = tid;
        int i = sidx[j];
        float stride, cx, cy;
        prior_of(i, stride, cx, cy);
        float4 bb = *(const float4*)(bbox + ((size_t)b * NANCH + (size_t)i) * 4);
        float x = bb.x * stride + cx;
        float y = bb.y * stride + cy;
        float w = expf(bb.z) * stride;
        float h = expf(bb.w) * stride;
        float x1 = x - 0.5f * w, y1 = y - 0.5f * h;
        float x2 = x + 0.5f * w, y2 = y + 0.5f * h;
        bx1[j] = x1; by1[j] = y1; bx2[j] = x2; by2[j] = y2;
        area[j] = fmaxf(x2 - x1, 0.0f) * fmaxf(y2 - y1, 0.0f);
    }
    __syncthreads();

    // ---- suppression bitmask, task = (row i, word w), <=64 inner iters ----
    for (int t = tid; t < NMSK * 5; t += NTHR) {
        int w = t / NMSK;
        int i = t - w * NMSK;
        int jlo = w * 64; if (jlo < i + 1) jlo = i + 1;
        int jhi = w * 64 + 64; if (jhi > NMSK) jhi = NMSK;
        unsigned long long m = 0;
        float ax1 = bx1[i], ay1 = by1[i], ax2 = bx2[i], ay2 = by2[i], aa = area[i];
        for (int j = jlo; j < jhi; ++j) {
            float lx = fmaxf(ax1, bx1[j]);
            float ly = fmaxf(ay1, by1[j]);
            float rx = fminf(ax2, bx2[j]);
            float ry = fminf(ay2, by2[j]);
            float iw = fmaxf(rx - lx, 0.0f);
            float ih = fmaxf(ry - ly, 0.0f);
            float inter = iw * ih;
            float iou = inter / (aa + area[j] - inter + 1e-7f);
            if (iou > 0.65f) m |= 1ull << (j & 63);
        }
        supl[i * 6 + w] = m;
    }
    __syncthreads();

    // ---- wave0: readlane greedy scan || others: sidx + cols 0-3 ----
    if (tid < 64) {
        int j = tid;
        unsigned long long keep0 = ~0ull, keep1 = ~0ull, keep2 = ~0ull, keep3 = ~0ull;
        unsigned long long keep4 = (1ull << (NMSK - 256)) - 1ull;
        // chunk c: lane j holds mask row c*64+j (5 u64 words, split lo/hi).
        // keepN stay wave-uniform (updated only via readlane results) -> SGPRs,
        // so each step's chain is readlane (~VALU latency) not LDS (~120cy).
        #define CHUNK(C, KC, IMAX) { \
            int r = (C) * 64 + j; \
            unsigned int lo0=0,hi0=0,lo1=0,hi1=0,lo2=0,hi2=0,lo3=0,hi3=0,lo4=0,hi4=0; \
            if (r < NMSK) { \
                unsigned long long w0 = supl[r*6+0], w1 = supl[r*6+1], w2 = supl[r*6+2]; \
                unsigned long long w3 = supl[r*6+3], w4 = supl[r*6+4]; \
                lo0=(unsigned int)w0; hi0=(unsigned int)(w0>>32); \
                lo1=(unsigned int)w1; hi1=(unsigned int)(w1>>32); \
                lo2=(unsigned int)w2; hi2=(unsigned int)(w2>>32); \
                lo3=(unsigned int)w3; hi3=(unsigned int)(w3>>32); \
                lo4=(unsigned int)w4; hi4=(unsigned int)(w4>>32); } \
            for (int bi = 0; bi < (IMAX); ++bi) { \
                if ((KC >> bi) & 1ull) { \
                    unsigned long long s0 = ((unsigned long long)__builtin_amdgcn_readlane(hi0,bi)<<32) | __builtin_amdgcn_readlane(lo0,bi); \
                    unsigned long long s1 = ((unsigned long long)__builtin_amdgcn_readlane(hi1,bi)<<32) | __builtin_amdgcn_readlane(lo1,bi); \
                    unsigned long long s2 = ((unsigned long long)__builtin_amdgcn_readlane(hi2,bi)<<32) | __builtin_amdgcn_readlane(lo2,bi); \
                    unsigned long long s3 = ((unsigned long long)__builtin_amdgcn_readlane(hi3,bi)<<32) | __builtin_amdgcn_readlane(lo3,bi); \
                    unsigned long long s4 = ((unsigned long long)__builtin_amdgcn_readlane(hi4,bi)<<32) | __builtin_amdgcn_readlane(lo4,bi); \
                    keep0 &= ~s0; keep1 &= ~s1; keep2 &= ~s2; keep3 &= ~s3; keep4 &= ~s4; } } }
        CHUNK(0, keep0, 64)
        CHUNK(1, keep1, 64)
        CHUNK(2, keep2, 64)
        CHUNK(3, keep3, 64)
        CHUNK(4, keep4, NMSK - 256)
        #undef CHUNK
        if (j == 0) { keepw[0]=keep0; keepw[1]=keep1; keepw[2]=keep2; keepw[3]=keep3; keepw[4]=keep4; }
    } else {
        int* sg = sidx_g + (size_t)b * NMSK;
        float* ob = out + (size_t)b * NMSK * OUTC;
        for (int t = tid - 64; t < NMSK; t += NTHR - 64) sg[t] = sidx[t];
        for (int t = tid - 64; t < NMSK * 4; t += NTHR - 64) {
            int j = t >> 2, ci = t & 3;
            float vv = (ci == 0) ? bx1[j] : (ci == 1) ? by1[j] : (ci == 2) ? bx2[j] : by2[j];
            ob[j * OUTC + ci] = vv;
        }
    }
    __syncthreads();

    // ---- col 4: keep-masked score ----
    if (tid < NMSK) {
        bool kp = (keepw[tid >> 6] >> (tid & 63)) & 1ull;
        out[(size_t)b * NMSK * OUTC + (size_t)tid * OUTC + 4] = kp ? sval[tid] : 0.0f;
    }
}

// ---------------------------------------------------------------------------
// K3: kpt/vis gathers, cols 5..55. 256 blocks x 512 (2 blocks per batch) ->
// all 256 CUs. Priors recomputed from sidx (same formula -> bit-exact).
// ---------------------------------------------------------------------------
__global__ __launch_bounds__(512) void kpt_kernel(
    const int* __restrict__ sidx_g, const float* __restrict__ kofs,
    const float* __restrict__ kvis, float* __restrict__ out)
{
    const int b = blockIdx.x >> 1;
    const int h = blockIdx.x & 1;
    const int tid = threadIdx.x;
    __shared__ int si[NMSK];
    if (tid < NMSK) si[tid] = sidx_g[(size_t)b * NMSK + tid];
    __syncthreads();
    const float* kof = kofs + (size_t)b * NANCH * 34;
    const float* kvi = kvis + (size_t)b * NANCH * KPT;
    float* ob = out + (size_t)b * NMSK * OUTC;
    const int half = (NMSK * 51) / 2;   // 7650
    const int e0 = h * half;
    for (int e = e0 + tid; e < e0 + half; e += 512) {
        int j  = e / 51;
        int ci = e - j * 51;
        int i  = si[j];
        float stride, cx, cy;
        prior_of(i, stride, cx, cy);
        float v;
        if (ci < 34) {
            float off = kof[(size_t)i * 34 + ci];
            v = off * stride + ((ci & 1) ? cy : cx);
        } else {
            float x = kvi[(size_t)i * KPT + (ci - 34)];
            v = 1.0f / (1.0f + expf(-x));
        }
        ob[j * OUTC + 5 + ci] = v;
    }
}

// ---------------------------------------------------------------------------
extern "C" void kernel_launch(void* const* d_in, const int* in_sizes, int n_in,
                              void* d_out, int out_size, void* d_ws, size_t ws_size,
                              hipStream_t stream) {
    const float* cls  = (const float*)d_in[0];  // [B,N,1]
    const float* bbox = (const float*)d_in[1];  // [B,N,4]
    const float* obj  = (const float*)d_in[2];  // [B,N]
    const float* kofs = (const float*)d_in[3];  // [B,N,17,2]
    const float* kvis = (const float*)d_in[4];  // [B,N,17]
    float* out = (float*)d_out;                 // [B,300,56]

    // Workspace layout (poison fill is unconditional -> ws use is free):
    //   [0, 4.3MB)   sc bits  uint[B][N]
    //   [4.3MB, ..)  sidx     int[B][300]
    unsigned int* sc = (unsigned int*)d_ws;
    int* sidx_g = (int*)((char*)d_ws + (size_t)BATCH * NANCH * sizeof(unsigned int));

    scores_kernel<<<(BATCH * NANCH / 4) / 256, 256, 0, stream>>>(cls, obj, sc);
    select_kernel<<<BATCH, NTHR, 0, stream>>>(sc, bbox, out, sidx_g);
    kpt_kernel<<<BATCH * 2, 512, 0, stream>>>(sidx_g, kofs, kvis, out);
}

// Round 5
// 296.554 us; speedup vs baseline: 1.0984x; 1.0984x over previous
//
#include <hip/hip_runtime.h>
#include <math.h>

#define BATCH 128
#define NANCH 8400
#define NMSK  300
#define KPT   17
#define OUTC  56    // 4 box + 1 score + 34 kpt + 17 vis
#define CAND  1024  // candidate slots (>=300 + 13-bit-bin tie margin)
#define NTHR  1024
#define NBIN  8192  // 13-bit bins: top bits of positive f32 (monotone)
#define BSHIFT 19

__device__ __forceinline__ void prior_of(int i, float& stride, float& cx, float& cy) {
    int row, col;
    if (i < 6400)      { stride = 8.0f;  row = i / 80;              col = i - row * 80; }
    else if (i < 8000) { int ii = i - 6400; stride = 16.0f; row = ii / 40; col = ii - row * 40; }
    else               { int ii = i - 8000; stride = 32.0f; row = ii / 20; col = ii - row * 20; }
    cx = ((float)col + 0.5f) * stride;
    cy = ((float)row + 0.5f) * stride;
}

// ---------------------------------------------------------------------------
// Single launch, 256 blocks x 1024 (full chip, 1 block/CU). Two blocks per
// batch: both run the identical cheap HEAD (in-block bit-exact scores ->
// single-pass 8192-bin histogram select -> compact -> rank; deterministic, so
// both derive the same sidx/sval). Then:
//   role 0: box decode -> NMS bitmask -> readlane greedy scan -> cols 0..4
//   role 1: prior decode -> kpt/vis gather -> cols 5..55
// Disjoint output columns -> no races. All mechanisms correctness-verified:
//   score math + decode + bitmask (R2/R3, absmax 0.0), 13-bit histogram
//   select + readlane scan (R4, absmax 0.0).
// R4 lesson: extra dependent launches cost more than they buy -> ONE launch.
// R3 lesson: workspace poison fill is unconditional; d_ws unused here anyway.
// ---------------------------------------------------------------------------
__global__ __launch_bounds__(NTHR) void fused_kernel(
    const float* __restrict__ cls, const float* __restrict__ obj,
    const float* __restrict__ bbox, const float* __restrict__ kofs,
    const float* __restrict__ kvis, float* __restrict__ out)
{
    const int b    = blockIdx.x >> 1;
    const int role = blockIdx.x & 1;
    const int tid  = threadIdx.x;
    const int lane = tid & 63;
    const int wv   = tid >> 6;

    __shared__ __align__(16) unsigned int sc[NANCH];     // 33600 B
    __shared__ __align__(16) unsigned int hist[NBIN];    // 32768 B (becomes suf)
    __shared__ unsigned int wtot[16], wab[16];
    __shared__ unsigned int sh_pivot, sh_cnt;
    __shared__ unsigned long long ckey[CAND];            // 8192 B
    __shared__ float bx1[NMSK], by1[NMSK], bx2[NMSK], by2[NMSK], area[NMSK];
    __shared__ float sval[NMSK], pst[NMSK], ppx[NMSK], ppy[NMSK];
    __shared__ int   sidx[NMSK];
    __shared__ unsigned long long supl[NMSK * 6];        // 14400 B
    __shared__ unsigned long long keepw[5];

    // ======================= HEAD (both roles) =======================
    // ---- in-block score bits (bit-exact: f64 exp -> f32) + zero hist ----
    {
        const float4* c4 = (const float4*)(cls + (size_t)b * NANCH);
        const float4* o4 = (const float4*)(obj + (size_t)b * NANCH);
        for (int i = tid; i < NANCH / 4; i += NTHR) {
            float4 cv = c4[i];
            float4 ov = o4[i];
            float sa0 = 1.0f / (1.0f + (float)exp(-(double)cv.x));
            float sa1 = 1.0f / (1.0f + (float)exp(-(double)cv.y));
            float sa2 = 1.0f / (1.0f + (float)exp(-(double)cv.z));
            float sa3 = 1.0f / (1.0f + (float)exp(-(double)cv.w));
            float so0 = 1.0f / (1.0f + (float)exp(-(double)ov.x));
            float so1 = 1.0f / (1.0f + (float)exp(-(double)ov.y));
            float so2 = 1.0f / (1.0f + (float)exp(-(double)ov.z));
            float so3 = 1.0f / (1.0f + (float)exp(-(double)ov.w));
            sc[4 * i + 0] = __float_as_uint(sa0 * so0);
            sc[4 * i + 1] = __float_as_uint(sa1 * so1);
            sc[4 * i + 2] = __float_as_uint(sa2 * so2);
            sc[4 * i + 3] = __float_as_uint(sa3 * so3);
        }
        uint4 z; z.x = z.y = z.z = z.w = 0u;
        uint4* h4 = (uint4*)hist;
        for (int i = tid; i < NBIN / 4; i += NTHR) h4[i] = z;
        if (tid == 0) sh_cnt = 0u;
    }
    __syncthreads();

    // ---- 8192-bin histogram ----
    for (int i = tid; i < NANCH; i += NTHR) atomicAdd(&hist[sc[i] >> BSHIFT], 1u);
    __syncthreads();

    // ---- suffix scan (in-place): thread owns bins [8t, 8t+8) ----
    unsigned int s7[8];
    {
        uint4 a = ((uint4*)hist)[2 * tid];
        uint4 c = ((uint4*)hist)[2 * tid + 1];
        unsigned int h0 = a.x, h1 = a.y, h2 = a.z, h3 = a.w;
        unsigned int h4 = c.x, h5 = c.y, h6 = c.z, h7 = c.w;
        s7[7] = h7;
        s7[6] = s7[7] + h6; s7[5] = s7[6] + h5; s7[4] = s7[5] + h4;
        s7[3] = s7[4] + h3; s7[2] = s7[3] + h2; s7[1] = s7[2] + h1;
        s7[0] = s7[1] + h0;
    }
    unsigned int T = s7[0];
    unsigned int v = T;
    #pragma unroll
    for (int d = 1; d < 64; d <<= 1) {
        unsigned int t2 = (unsigned int)__shfl_down((int)v, d, 64);
        if (lane + d < 64) v += t2;       // inclusive suffix over lanes >= lane
    }
    unsigned int aiw = v - T;             // sum over lanes > lane
    if (lane == 0) wtot[wv] = v;
    __syncthreads();
    if (tid < 16) {
        unsigned int wa = 0;
        for (int q = tid + 1; q < 16; ++q) wa += wtot[q];
        wab[tid] = wa;                    // sum over waves > w
    }
    __syncthreads();
    {
        unsigned int ag = wab[wv] + aiw;
        #pragma unroll
        for (int k = 0; k < 8; ++k) hist[8 * tid + k] = ag + s7[k];  // hist := suf
    }
    __syncthreads();

    // ---- pivot: unique bin with suf[p] >= 300 > suf[p+1] ----
    #pragma unroll
    for (int k = 0; k < 8; ++k) {
        unsigned int bin = 8 * (unsigned)tid + k;
        unsigned int ge = hist[bin];
        unsigned int gn = (bin < NBIN - 1) ? hist[bin + 1] : 0u;
        if (ge >= NMSK && gn < NMSK) sh_pivot = bin;
    }
    __syncthreads();
    unsigned int pivot_bits = sh_pivot << BSHIFT;

    // ---- compact all keys >= pivot (wave-aggregated counter) ----
    for (int base = 0; base < NANCH; base += NTHR) {
        int i = base + tid;
        bool valid = (i < NANCH);
        unsigned int key = valid ? sc[i] : 0u;
        bool pred = valid && (key >= pivot_bits);
        unsigned long long m = __ballot(pred);
        unsigned int cnt = (unsigned int)__popcll(m);
        unsigned int wbase = 0u;
        if (lane == 0 && cnt) wbase = atomicAdd(&sh_cnt, cnt);
        wbase = (unsigned int)__shfl((int)wbase, 0, 64);
        if (pred) {
            unsigned int p = wbase + (unsigned int)__popcll(m & ((1ull << lane) - 1ull));
            if (p < CAND)
                ckey[p] = ((unsigned long long)key << 32)
                        | (unsigned long long)(0xFFFFFFFFu - (unsigned int)i);
        }
    }
    __syncthreads();
    unsigned int M = sh_cnt; if (M > CAND) M = CAND;

    // ---- rank order (score desc, idx asc == lax.top_k); deterministic ----
    if (tid < (int)M) {
        unsigned long long mine = ckey[tid];
        int rank = 0;
        for (unsigned int t2 = 0; t2 < M; ++t2) rank += (ckey[t2] > mine) ? 1 : 0;
        if (rank < NMSK) {
            sidx[rank] = (int)(0xFFFFFFFFu - (unsigned int)(mine & 0xFFFFFFFFull));
            sval[rank] = __uint_as_float((unsigned int)(mine >> 32));
        }
    }
    __syncthreads();

    // ======================= TAILS (role-split) =======================
    if (role == 0) {
        // ---- decode the 300 boxes ----
        if (tid < NMSK) {
            int j = tid;
            int i = sidx[j];
            float stride, cx, cy;
            prior_of(i, stride, cx, cy);
            float4 bb = *(const float4*)(bbox + ((size_t)b * NANCH + (size_t)i) * 4);
            float x = bb.x * stride + cx;
            float y = bb.y * stride + cy;
            float w = expf(bb.z) * stride;
            float h = expf(bb.w) * stride;
            float x1 = x - 0.5f * w, y1 = y - 0.5f * h;
            float x2 = x + 0.5f * w, y2 = y + 0.5f * h;
            bx1[j] = x1; by1[j] = y1; bx2[j] = x2; by2[j] = y2;
            area[j] = fmaxf(x2 - x1, 0.0f) * fmaxf(y2 - y1, 0.0f);
        }
        __syncthreads();

        // ---- suppression bitmask, task = (row i, word w) ----
        for (int t = tid; t < NMSK * 5; t += NTHR) {
            int w = t / NMSK;
            int i = t - w * NMSK;
            int jlo = w * 64; if (jlo < i + 1) jlo = i + 1;
            int jhi = w * 64 + 64; if (jhi > NMSK) jhi = NMSK;
            unsigned long long m = 0;
            float ax1 = bx1[i], ay1 = by1[i], ax2 = bx2[i], ay2 = by2[i], aa = area[i];
            for (int j = jlo; j < jhi; ++j) {
                float lx = fmaxf(ax1, bx1[j]);
                float ly = fmaxf(ay1, by1[j]);
                float rx = fminf(ax2, bx2[j]);
                float ry = fminf(ay2, by2[j]);
                float iw = fmaxf(rx - lx, 0.0f);
                float ih = fmaxf(ry - ly, 0.0f);
                float inter = iw * ih;
                float iou = inter / (aa + area[j] - inter + 1e-7f);
                if (iou > 0.65f) m |= 1ull << (j & 63);
            }
            supl[i * 6 + w] = m;
        }
        __syncthreads();

        // ---- wave0: readlane greedy scan || others: cols 0-3 ----
        if (tid < 64) {
            int j = tid;
            unsigned long long keep0 = ~0ull, keep1 = ~0ull, keep2 = ~0ull, keep3 = ~0ull;
            unsigned long long keep4 = (1ull << (NMSK - 256)) - 1ull;
            // keepN stay wave-uniform (updated only via readlane) -> SGPR chain
            #define CHUNK(C, KC, IMAX) { \
                int r = (C) * 64 + j; \
                unsigned int lo0=0,hi0=0,lo1=0,hi1=0,lo2=0,hi2=0,lo3=0,hi3=0,lo4=0,hi4=0; \
                if (r < NMSK) { \
                    unsigned long long w0 = supl[r*6+0], w1 = supl[r*6+1], w2 = supl[r*6+2]; \
                    unsigned long long w3 = supl[r*6+3], w4 = supl[r*6+4]; \
                    lo0=(unsigned int)w0; hi0=(unsigned int)(w0>>32); \
                    lo1=(unsigned int)w1; hi1=(unsigned int)(w1>>32); \
                    lo2=(unsigned int)w2; hi2=(unsigned int)(w2>>32); \
                    lo3=(unsigned int)w3; hi3=(unsigned int)(w3>>32); \
                    lo4=(unsigned int)w4; hi4=(unsigned int)(w4>>32); } \
                for (int bi = 0; bi < (IMAX); ++bi) { \
                    if ((KC >> bi) & 1ull) { \
                        unsigned long long s0 = ((unsigned long long)__builtin_amdgcn_readlane(hi0,bi)<<32) | __builtin_amdgcn_readlane(lo0,bi); \
                        unsigned long long s1 = ((unsigned long long)__builtin_amdgcn_readlane(hi1,bi)<<32) | __builtin_amdgcn_readlane(lo1,bi); \
                        unsigned long long s2 = ((unsigned long long)__builtin_amdgcn_readlane(hi2,bi)<<32) | __builtin_amdgcn_readlane(lo2,bi); \
                        unsigned long long s3 = ((unsigned long long)__builtin_amdgcn_readlane(hi3,bi)<<32) | __builtin_amdgcn_readlane(lo3,bi); \
                        unsigned long long s4 = ((unsigned long long)__builtin_amdgcn_readlane(hi4,bi)<<32) | __builtin_amdgcn_readlane(lo4,bi); \
                        keep0 &= ~s0; keep1 &= ~s1; keep2 &= ~s2; keep3 &= ~s3; keep4 &= ~s4; } } }
            CHUNK(0, keep0, 64)
            CHUNK(1, keep1, 64)
            CHUNK(2, keep2, 64)
            CHUNK(3, keep3, 64)
            CHUNK(4, keep4, NMSK - 256)
            #undef CHUNK
            if (j == 0) { keepw[0]=keep0; keepw[1]=keep1; keepw[2]=keep2; keepw[3]=keep3; keepw[4]=keep4; }
        } else {
            float* ob = out + (size_t)b * NMSK * OUTC;
            for (int t = tid - 64; t < NMSK * 4; t += NTHR - 64) {
                int j = t >> 2, ci = t & 3;
                float vv = (ci == 0) ? bx1[j] : (ci == 1) ? by1[j] : (ci == 2) ? bx2[j] : by2[j];
                ob[j * OUTC + ci] = vv;
            }
        }
        __syncthreads();

        // ---- col 4: keep-masked score ----
        if (tid < NMSK) {
            bool kp = (keepw[tid >> 6] >> (tid & 63)) & 1ull;
            out[(size_t)b * NMSK * OUTC + (size_t)tid * OUTC + 4] = kp ? sval[tid] : 0.0f;
        }
    } else {
        // ---- role 1: priors for the 300 rows ----
        if (tid < NMSK) {
            int i = sidx[tid];
            float stride, cx, cy;
            prior_of(i, stride, cx, cy);
            pst[tid] = stride; ppx[tid] = cx; ppy[tid] = cy;
        }
        __syncthreads();

        // ---- cols 5..55: gathered kpt decode + vis sigmoid, 1024 threads ----
        const float* kof = kofs + (size_t)b * NANCH * 34;
        const float* kvi = kvis + (size_t)b * NANCH * KPT;
        float* ob = out + (size_t)b * NMSK * OUTC;
        for (int e = tid; e < NMSK * 51; e += NTHR) {
            int j  = e / 51;
            int ci = e - j * 51;
            int i  = sidx[j];
            float vv;
            if (ci < 34) {
                float off = kof[(size_t)i * 34 + ci];
                vv = off * pst[j] + ((ci & 1) ? ppy[j] : ppx[j]);
            } else {
                float x = kvi[(size_t)i * KPT + (ci - 34)];
                vv = 1.0f / (1.0f + expf(-x));
            }
            ob[j * OUTC + 5 + ci] = vv;
        }
    }
}

// ---------------------------------------------------------------------------
extern "C" void kernel_launch(void* const* d_in, const int* in_sizes, int n_in,
                              void* d_out, int out_size, void* d_ws, size_t ws_size,
                              hipStream_t stream) {
    const float* cls  = (const float*)d_in[0];  // [B,N,1]
    const float* bbox = (const float*)d_in[1];  // [B,N,4]
    const float* obj  = (const float*)d_in[2];  // [B,N]
    const float* kofs = (const float*)d_in[3];  // [B,N,17,2]
    const float* kvis = (const float*)d_in[4];  // [B,N,17]
    float* out = (float*)d_out;                 // [B,300,56]

    (void)d_ws; (void)ws_size;  // poison fill is unconditional; single launch

    fused_kernel<<<BATCH * 2, NTHR, 0, stream>>>(cls, obj, bbox, kofs, kvis, out);
}

// Round 6
// 296.187 us; speedup vs baseline: 1.0997x; 1.0012x over previous
//
#include <hip/hip_runtime.h>
#include <math.h>

#define BATCH 128
#define NANCH 8400
#define NMSK  300
#define KPT   17
#define OUTC  56    // 4 box + 1 score + 34 kpt + 17 vis
#define CAND  1024  // candidate slots (>=300 + 13-bit-bin tie margin)
#define NTHR  1024
#define NBIN  8192  // 13-bit bins: top bits of positive f32 (monotone)
#define BSHIFT 19
#define NGRP  (NANCH / 4)   // 2100 uint4 groups

__device__ __forceinline__ void prior_of(int i, float& stride, float& cx, float& cy) {
    int row, col;
    if (i < 6400)      { stride = 8.0f;  row = i / 80;              col = i - row * 80; }
    else if (i < 8000) { int ii = i - 6400; stride = 16.0f; row = ii / 40; col = ii - row * 40; }
    else               { int ii = i - 8000; stride = 32.0f; row = ii / 20; col = ii - row * 20; }
    cx = ((float)col + 0.5f) * stride;
    cy = ((float)row + 0.5f) * stride;
}

// ---------------------------------------------------------------------------
// Single launch, 128 blocks x 1024 (one block per batch). R5 lesson: head
// duplication across 2 blocks/batch costs more than tail-splitting saves.
// R6 structure (9 barriers, down from 12):
//   scores -> REGISTERS (no sc[] LDS staging / re-reads)
//   8192-bin histogram (plain LDS atomics; low clustering at 13-bit bins)
//   suffix scan with LOCAL pivot detection (no suf write-back phase)
//   compact from registers (ballot-aggregated; any order -- rank is a total
//   order on (key,idx) so compaction permutation is irrelevant)
//   rank + FUSED box decode
//   NMS bitmask -> (wave0 ROLLED readlane greedy scan || waves1-15 kpt/vis +
//   cols0-3) -> col4.
// All math bit-exact-verified in prior rounds (absmax 0.0): score f64-exp
// formula (R2/R3), histogram select + readlane scan (R4/R5), kpt with
// recomputed priors (R4). d_ws unused (poison fill is unconditional anyway).
// ---------------------------------------------------------------------------
__global__ __launch_bounds__(NTHR) void fused_kernel(
    const float* __restrict__ cls, const float* __restrict__ obj,
    const float* __restrict__ bbox, const float* __restrict__ kofs,
    const float* __restrict__ kvis, float* __restrict__ out)
{
    const int b    = blockIdx.x;
    const int tid  = threadIdx.x;
    const int lane = tid & 63;
    const int wv   = tid >> 6;

    __shared__ __align__(16) unsigned int hist[NBIN];    // 32768 B
    __shared__ unsigned int wtot[16], wab[16];
    __shared__ unsigned int sh_pivot, sh_cnt;
    __shared__ unsigned long long ckey[CAND];            // 8192 B
    __shared__ float bx1[NMSK], by1[NMSK], bx2[NMSK], by2[NMSK], area[NMSK];
    __shared__ float sval[NMSK];
    __shared__ int   sidx[NMSK];
    __shared__ unsigned long long supl[NMSK * 6];        // 14400 B
    __shared__ unsigned long long keepw[5];

    // ---- phase 1: scores into registers (bit-exact f64 exp) + zero hist ----
    unsigned int sck[12];   // 3 uint4 groups x 4 keys; static indexing only
    {
        const float4* c4 = (const float4*)(cls + (size_t)b * NANCH);
        const float4* o4 = (const float4*)(obj + (size_t)b * NANCH);
        #pragma unroll
        for (int k = 0; k < 3; ++k) {
            int g = tid + k * NTHR;
            if (g < NGRP) {
                float4 cv = c4[g];
                float4 ov = o4[g];
                float sa0 = 1.0f / (1.0f + (float)exp(-(double)cv.x));
                float sa1 = 1.0f / (1.0f + (float)exp(-(double)cv.y));
                float sa2 = 1.0f / (1.0f + (float)exp(-(double)cv.z));
                float sa3 = 1.0f / (1.0f + (float)exp(-(double)cv.w));
                float so0 = 1.0f / (1.0f + (float)exp(-(double)ov.x));
                float so1 = 1.0f / (1.0f + (float)exp(-(double)ov.y));
                float so2 = 1.0f / (1.0f + (float)exp(-(double)ov.z));
                float so3 = 1.0f / (1.0f + (float)exp(-(double)ov.w));
                sck[4 * k + 0] = __float_as_uint(sa0 * so0);
                sck[4 * k + 1] = __float_as_uint(sa1 * so1);
                sck[4 * k + 2] = __float_as_uint(sa2 * so2);
                sck[4 * k + 3] = __float_as_uint(sa3 * so3);
            } else {
                sck[4 * k + 0] = 0u; sck[4 * k + 1] = 0u;
                sck[4 * k + 2] = 0u; sck[4 * k + 3] = 0u;
            }
        }
        uint4 z; z.x = z.y = z.z = z.w = 0u;
        uint4* h4 = (uint4*)hist;
        h4[tid] = z;               // 8192 words = 2048 uint4; 2 per thread
        h4[tid + NTHR] = z;
        if (tid == 0) sh_cnt = 0u;
    }
    __syncthreads();

    // ---- phase 2: 8192-bin histogram from registers ----
    #pragma unroll
    for (int k = 0; k < 3; ++k) {
        int g = tid + k * NTHR;
        if (g < NGRP) {
            atomicAdd(&hist[sck[4 * k + 0] >> BSHIFT], 1u);
            atomicAdd(&hist[sck[4 * k + 1] >> BSHIFT], 1u);
            atomicAdd(&hist[sck[4 * k + 2] >> BSHIFT], 1u);
            atomicAdd(&hist[sck[4 * k + 3] >> BSHIFT], 1u);
        }
    }
    __syncthreads();

    // ---- phase 3: suffix scan; thread owns bins [8t, 8t+8) ----
    unsigned int s7[8];
    {
        uint4 a = ((uint4*)hist)[2 * tid];
        uint4 c = ((uint4*)hist)[2 * tid + 1];
        s7[7] = c.w;
        s7[6] = s7[7] + c.z; s7[5] = s7[6] + c.y; s7[4] = s7[5] + c.x;
        s7[3] = s7[4] + a.w; s7[2] = s7[3] + a.z; s7[1] = s7[2] + a.y;
        s7[0] = s7[1] + a.x;
    }
    unsigned int T = s7[0];
    unsigned int v = T;
    #pragma unroll
    for (int d = 1; d < 64; d <<= 1) {
        unsigned int t2 = (unsigned int)__shfl_down((int)v, d, 64);
        if (lane + d < 64) v += t2;       // inclusive suffix over lanes >= lane
    }
    unsigned int aiw = v - T;             // sum over lanes > lane
    if (lane == 0) wtot[wv] = v;
    __syncthreads();
    if (tid < 16) {
        unsigned int wa = 0;
        for (int q = tid + 1; q < 16; ++q) wa += wtot[q];
        wab[tid] = wa;                    // sum over waves > w
    }
    __syncthreads();

    // ---- phase 4: LOCAL pivot detection (no suf write-back) ----
    // suf[8t+k] = ag + s7[k]; suf[8t+8] = ag. Unique bin with
    // suf >= 300 > suf_next.
    {
        unsigned int ag = wab[wv] + aiw;
        #pragma unroll
        for (int k = 0; k < 8; ++k) {
            unsigned int ge = ag + s7[k];
            unsigned int gn = (k < 7) ? (ag + s7[k + 1]) : ag;
            if (ge >= NMSK && gn < NMSK) sh_pivot = 8u * (unsigned)tid + (unsigned)k;
        }
    }
    __syncthreads();
    unsigned int pivot_bits = sh_pivot << BSHIFT;

    // ---- phase 5: compact from registers (wave-aggregated counter) ----
    #pragma unroll
    for (int k = 0; k < 3; ++k) {
        int g = tid + k * NTHR;
        bool valid = (g < NGRP);
        #pragma unroll
        for (int s = 0; s < 4; ++s) {
            unsigned int key = sck[4 * k + s];
            bool pred = valid && (key >= pivot_bits);
            unsigned long long m = __ballot(pred);
            unsigned int cnt = (unsigned int)__popcll(m);
            unsigned int wbase = 0u;
            if (lane == 0 && cnt) wbase = atomicAdd(&sh_cnt, cnt);
            wbase = (unsigned int)__shfl((int)wbase, 0, 64);
            if (pred) {
                unsigned int p = wbase + (unsigned int)__popcll(m & ((1ull << lane) - 1ull));
                unsigned int idx = 4u * (unsigned)g + (unsigned)s;
                if (p < CAND)
                    ckey[p] = ((unsigned long long)key << 32)
                            | (unsigned long long)(0xFFFFFFFFu - idx);
            }
        }
    }
    __syncthreads();
    unsigned int M = sh_cnt; if (M > CAND) M = CAND;

    // ---- phase 6: rank order (score desc, idx asc) + FUSED box decode ----
    if (tid < (int)M) {
        unsigned long long mine = ckey[tid];
        int rank = 0;
        for (unsigned int t2 = 0; t2 < M; ++t2) rank += (ckey[t2] > mine) ? 1 : 0;
        if (rank < NMSK) {
            int i = (int)(0xFFFFFFFFu - (unsigned int)(mine & 0xFFFFFFFFull));
            sidx[rank] = i;
            sval[rank] = __uint_as_float((unsigned int)(mine >> 32));
            float stride, cx, cy;
            prior_of(i, stride, cx, cy);
            float4 bb = *(const float4*)(bbox + ((size_t)b * NANCH + (size_t)i) * 4);
            float x = bb.x * stride + cx;
            float y = bb.y * stride + cy;
            float w = expf(bb.z) * stride;
            float h = expf(bb.w) * stride;
            float x1 = x - 0.5f * w, y1 = y - 0.5f * h;
            float x2 = x + 0.5f * w, y2 = y + 0.5f * h;
            bx1[rank] = x1; by1[rank] = y1; bx2[rank] = x2; by2[rank] = y2;
            area[rank] = fmaxf(x2 - x1, 0.0f) * fmaxf(y2 - y1, 0.0f);
        }
    }
    __syncthreads();

    // ---- phase 7: suppression bitmask, task = (row i, word w) ----
    for (int t = tid; t < NMSK * 5; t += NTHR) {
        int w = t / NMSK;
        int i = t - w * NMSK;
        int jlo = w * 64; if (jlo < i + 1) jlo = i + 1;
        int jhi = w * 64 + 64; if (jhi > NMSK) jhi = NMSK;
        unsigned long long m = 0;
        float ax1 = bx1[i], ay1 = by1[i], ax2 = bx2[i], ay2 = by2[i], aa = area[i];
        for (int j = jlo; j < jhi; ++j) {
            float lx = fmaxf(ax1, bx1[j]);
            float ly = fmaxf(ay1, by1[j]);
            float rx = fminf(ax2, bx2[j]);
            float ry = fminf(ay2, by2[j]);
            float iw = fmaxf(rx - lx, 0.0f);
            float ih = fmaxf(ry - ly, 0.0f);
            float inter = iw * ih;
            float iou = inter / (aa + area[j] - inter + 1e-7f);
            if (iou > 0.65f) m |= 1ull << (j & 63);
        }
        supl[i * 6 + w] = m;
    }
    __syncthreads();

    // ---- phase 8: wave0 ROLLED readlane greedy || others kpt/vis+cols0-3 ----
    if (tid < 64) {
        int j = tid;
        unsigned long long keep0 = ~0ull, keep1 = ~0ull, keep2 = ~0ull, keep3 = ~0ull;
        unsigned long long keep4 = (1ull << (NMSK - 256)) - 1ull;
        // keepN stay wave-uniform (updated only via readlane) -> SGPR chain.
        // Inner loops rolled: readlane takes a runtime lane index; this cuts
        // ~7500 straight-line instructions to ~200 (icache theory).
        #define CHUNK(C, KC, IMAX) { \
            int r = (C) * 64 + j; \
            unsigned int lo0=0,hi0=0,lo1=0,hi1=0,lo2=0,hi2=0,lo3=0,hi3=0,lo4=0,hi4=0; \
            if (r < NMSK) { \
                unsigned long long w0 = supl[r*6+0], w1 = supl[r*6+1], w2 = supl[r*6+2]; \
                unsigned long long w3 = supl[r*6+3], w4 = supl[r*6+4]; \
                lo0=(unsigned int)w0; hi0=(unsigned int)(w0>>32); \
                lo1=(unsigned int)w1; hi1=(unsigned int)(w1>>32); \
                lo2=(unsigned int)w2; hi2=(unsigned int)(w2>>32); \
                lo3=(unsigned int)w3; hi3=(unsigned int)(w3>>32); \
                lo4=(unsigned int)w4; hi4=(unsigned int)(w4>>32); } \
            _Pragma("clang loop unroll(disable)") \
            for (int bi = 0; bi < (IMAX); ++bi) { \
                if ((KC >> bi) & 1ull) { \
                    unsigned long long s0 = ((unsigned long long)__builtin_amdgcn_readlane(hi0,bi)<<32) | __builtin_amdgcn_readlane(lo0,bi); \
                    unsigned long long s1 = ((unsigned long long)__builtin_amdgcn_readlane(hi1,bi)<<32) | __builtin_amdgcn_readlane(lo1,bi); \
                    unsigned long long s2 = ((unsigned long long)__builtin_amdgcn_readlane(hi2,bi)<<32) | __builtin_amdgcn_readlane(lo2,bi); \
                    unsigned long long s3 = ((unsigned long long)__builtin_amdgcn_readlane(hi3,bi)<<32) | __builtin_amdgcn_readlane(lo3,bi); \
                    unsigned long long s4 = ((unsigned long long)__builtin_amdgcn_readlane(hi4,bi)<<32) | __builtin_amdgcn_readlane(lo4,bi); \
                    keep0 &= ~s0; keep1 &= ~s1; keep2 &= ~s2; keep3 &= ~s3; keep4 &= ~s4; } } }
        CHUNK(0, keep0, 64)
        CHUNK(1, keep1, 64)
        CHUNK(2, keep2, 64)
        CHUNK(3, keep3, 64)
        CHUNK(4, keep4, NMSK - 256)
        #undef CHUNK
        if (j == 0) { keepw[0]=keep0; keepw[1]=keep1; keepw[2]=keep2; keepw[3]=keep3; keepw[4]=keep4; }
    } else {
        const float* kof = kofs + (size_t)b * NANCH * 34;
        const float* kvi = kvis + (size_t)b * NANCH * KPT;
        float* ob = out + (size_t)b * NMSK * OUTC;
        // cols 0..3 from LDS box arrays
        for (int t = tid - 64; t < NMSK * 4; t += NTHR - 64) {
            int j = t >> 2, ci = t & 3;
            float vv = (ci == 0) ? bx1[j] : (ci == 1) ? by1[j] : (ci == 2) ? bx2[j] : by2[j];
            ob[j * OUTC + ci] = vv;
        }
        // cols 5..55: gathered kpt decode (priors recomputed) + vis sigmoid
        for (int e = tid - 64; e < NMSK * 51; e += NTHR - 64) {
            int j  = e / 51;
            int ci = e - j * 51;
            int i  = sidx[j];
            float vv;
            if (ci < 34) {
                float stride, cx, cy;
                prior_of(i, stride, cx, cy);
                float off = kof[(size_t)i * 34 + ci];
                vv = off * stride + ((ci & 1) ? cy : cx);
            } else {
                float x = kvi[(size_t)i * KPT + (ci - 34)];
                vv = 1.0f / (1.0f + expf(-x));
            }
            ob[j * OUTC + 5 + ci] = vv;
        }
    }
    __syncthreads();

    // ---- phase 9: col 4 (keep-masked score) ----
    if (tid < NMSK) {
        bool kp = (keepw[tid >> 6] >> (tid & 63)) & 1ull;
        out[(size_t)b * NMSK * OUTC + (size_t)tid * OUTC + 4] = kp ? sval[tid] : 0.0f;
    }
}

// ---------------------------------------------------------------------------
extern "C" void kernel_launch(void* const* d_in, const int* in_sizes, int n_in,
                              void* d_out, int out_size, void* d_ws, size_t ws_size,
                              hipStream_t stream) {
    const float* cls  = (const float*)d_in[0];  // [B,N,1]
    const float* bbox = (const float*)d_in[1];  // [B,N,4]
    const float* obj  = (const float*)d_in[2];  // [B,N]
    const float* kofs = (const float*)d_in[3];  // [B,N,17,2]
    const float* kvis = (const float*)d_in[4];  // [B,N,17]
    float* out = (float*)d_out;                 // [B,300,56]

    (void)d_ws; (void)ws_size;  // poison fill is unconditional; single launch

    fused_kernel<<<BATCH, NTHR, 0, stream>>>(cls, obj, bbox, kofs, kvis, out);
}